// Round 1
// baseline (11660.574 us; speedup 1.0000x reference)
//
#include <hip/hip_runtime.h>
#include <stdint.h>

#define TT 512
#define BB 64
#define II 512
#define HH 512
#define GG 2048   // 4H
#define KK 1024   // I + H

typedef short short8 __attribute__((ext_vector_type(8)));
typedef float floatx4 __attribute__((ext_vector_type(4)));

static constexpr size_t WCAT_BYTES = (size_t)2 * GG * KK * 2;   // 8 MB  bf16 [2][2048][1024]
static constexpr size_t XB_BYTES   = (size_t)TT * BB * II * 2;  // 32 MB bf16 [T][B][I]
static constexpr size_t HBUF_BYTES = (size_t)2 * 2 * BB * HH * 2; // 256 KB bf16 [2 dir][2 slot][B][H]
static constexpr size_t CNT_BYTES  = (size_t)2 * TT * 4;        // 4 KB  int [2][T]

__device__ __forceinline__ unsigned short f2bf(float f) {
  unsigned int u = __float_as_uint(f);
  unsigned int r = (u + 0x7fffu + ((u >> 16) & 1u)) >> 16;   // round-to-nearest-even
  return (unsigned short)r;
}

// ---- prep: weights -> bf16 concat [dir][n][k] (k = [W_ih | W_hh]); h0 -> hbuf slot0; zero counters
__global__ void prep_kernel(const float* __restrict__ Wih_f, const float* __restrict__ Whh_f,
                            const float* __restrict__ Wih_b, const float* __restrict__ Whh_b,
                            const float* __restrict__ h0,
                            unsigned short* __restrict__ wcat,
                            unsigned short* __restrict__ hbuf,
                            int* __restrict__ cnt)
{
  size_t tid0 = (size_t)blockIdx.x * blockDim.x + threadIdx.x;
  size_t stride = (size_t)gridDim.x * blockDim.x;

  const size_t WC = (size_t)2 * GG * KK;   // 4194304 = 2^22
  for (size_t idx = tid0; idx < WC; idx += stride) {
    int dir = (int)(idx >> 21);
    int rem = (int)(idx & ((1u << 21) - 1));
    int n = rem >> 10;
    int k = rem & 1023;
    const float* Wih = dir ? Wih_b : Wih_f;
    const float* Whh = dir ? Whh_b : Whh_f;
    float v = (k < II) ? Wih[(size_t)n * II + k] : Whh[(size_t)n * HH + (k - II)];
    wcat[idx] = f2bf(v);
  }

  const size_t HC = (size_t)2 * BB * HH;   // 65536
  for (size_t idx = tid0; idx < HC; idx += stride) {
    int dir = (int)(idx >> 15);
    int rem = (int)(idx & 32767);
    hbuf[(size_t)dir * 2 * BB * HH + rem] = f2bf(h0[idx]);  // slot 0
  }

  for (size_t idx = tid0; idx < (size_t)2 * TT; idx += stride) cnt[idx] = 0;
}

// ---- x -> bf16
__global__ void xconv_kernel(const float* __restrict__ x, unsigned short* __restrict__ xb) {
  size_t i = (size_t)blockIdx.x * blockDim.x + threadIdx.x;
  size_t stride = (size_t)gridDim.x * blockDim.x;
  const size_t n4 = (size_t)TT * BB * II / 4;
  const float4* xp = (const float4*)x;
  ushort4* op = (ushort4*)xb;
  for (; i < n4; i += stride) {
    float4 v = xp[i];
    ushort4 o;
    o.x = f2bf(v.x); o.y = f2bf(v.y); o.z = f2bf(v.z); o.w = f2bf(v.w);
    op[i] = o;
  }
}

// ---- persistent bidirectional LSTM
// grid = 64 blocks: dir = bid>>5 (0 fwd, 1 bwd), jslice16 = (bid&31)*16.
// 4 waves/block: wave w owns m-tile rows [16w,16w+16). Each wave computes 4 gate
// tiles (i,f,g,o) for its (m-tile, jslice) and keeps c for that tile in registers.
template<bool XBF16>
__global__ __launch_bounds__(256) void lstm_kernel(
    const float* __restrict__ x_f32,
    const unsigned short* __restrict__ xb,
    const unsigned short* __restrict__ wcat,
    unsigned short* __restrict__ hbuf,
    int* __restrict__ cnt,
    const float* __restrict__ c0,
    const float* __restrict__ b_f,
    const float* __restrict__ b_b,
    float* __restrict__ out)
{
  const int bid  = blockIdx.x;
  const int dir  = bid >> 5;
  const int j0   = (bid & 31) << 4;
  const int tid  = threadIdx.x;
  const int lane = tid & 63;
  const int l15  = lane & 15;
  const int quad = lane >> 4;
  const int m0   = (tid >> 6) << 4;

  const unsigned short* Wd = wcat + (size_t)dir * GG * KK;
  const float* bias = dir ? b_b : b_f;

  float bs[4];
#pragma unroll
  for (int g = 0; g < 4; ++g) bs[g] = bias[g * HH + j0 + l15];

  // c state lives in registers: C/D layout -> row = m0 + quad*4 + r, col = j0 + l15
  float cst[4];
#pragma unroll
  for (int r = 0; r < 4; ++r)
    cst[r] = c0[(size_t)dir * BB * HH + (size_t)(m0 + quad * 4 + r) * HH + j0 + l15];

  unsigned short* hb = hbuf + (size_t)dir * 2 * BB * HH;
  int* cn = cnt + dir * TT;

  // B-operand row pointers (W stored [n][k], k contiguous == MFMA B^T layout)
  const unsigned short* wrow[4];
#pragma unroll
  for (int g = 0; g < 4; ++g)
    wrow[g] = Wd + (size_t)(g * HH + j0 + l15) * KK + quad * 8;

  for (int t = 0; t < TT; ++t) {
    const int tt2 = dir ? (TT - 1 - t) : t;   // time index into x and out

    floatx4 acc[4];
#pragma unroll
    for (int g = 0; g < 4; ++g) acc[g] = (floatx4){0.f, 0.f, 0.f, 0.f};

    // ---- x contribution (k = 0..511): independent of h, runs before the wait ----
    if (XBF16) {
      const unsigned short* arow = xb + (size_t)tt2 * BB * II + (size_t)(m0 + l15) * II + quad * 8;
#pragma unroll
      for (int kc = 0; kc < 16; ++kc) {
        short8 a = *(const short8*)(arow + kc * 32);
#pragma unroll
        for (int g = 0; g < 4; ++g) {
          short8 b = *(const short8*)(wrow[g] + kc * 32);
          acc[g] = __builtin_amdgcn_mfma_f32_16x16x32_bf16(a, b, acc[g], 0, 0, 0);
        }
      }
    } else {
      const float* arow = x_f32 + (size_t)tt2 * BB * II + (size_t)(m0 + l15) * II + quad * 8;
#pragma unroll
      for (int kc = 0; kc < 16; ++kc) {
        float4 v0 = *(const float4*)(arow + kc * 32);
        float4 v1 = *(const float4*)(arow + kc * 32 + 4);
        short8 a;
        a[0] = (short)f2bf(v0.x); a[1] = (short)f2bf(v0.y);
        a[2] = (short)f2bf(v0.z); a[3] = (short)f2bf(v0.w);
        a[4] = (short)f2bf(v1.x); a[5] = (short)f2bf(v1.y);
        a[6] = (short)f2bf(v1.z); a[7] = (short)f2bf(v1.w);
#pragma unroll
        for (int g = 0; g < 4; ++g) {
          short8 b = *(const short8*)(wrow[g] + kc * 32);
          acc[g] = __builtin_amdgcn_mfma_f32_16x16x32_bf16(a, b, acc[g], 0, 0, 0);
        }
      }
    }

    // ---- wait for h_{t-1} from all 32 blocks of this direction ----
    if (t > 0) {
      if (tid == 0) {
        while (__hip_atomic_load(&cn[t - 1], __ATOMIC_ACQUIRE, __HIP_MEMORY_SCOPE_AGENT) < 32) { }
      }
      __syncthreads();
      __threadfence();   // agent acquire: invalidate stale L1/L2 before reading h
    }

    // ---- h contribution (k = 512..1023), slot = t&1 ----
    {
      const unsigned short* hrow = hb + (size_t)(t & 1) * BB * HH + (size_t)(m0 + l15) * HH + quad * 8;
#pragma unroll
      for (int kc = 0; kc < 16; ++kc) {
        short8 a = *(const short8*)(hrow + kc * 32);
#pragma unroll
        for (int g = 0; g < 4; ++g) {
          short8 b = *(const short8*)(wrow[g] + II + kc * 32);
          acc[g] = __builtin_amdgcn_mfma_f32_16x16x32_bf16(a, b, acc[g], 0, 0, 0);
        }
      }
    }

    // ---- gates + state update + outputs ----
    unsigned short* hout = hb + (size_t)((t + 1) & 1) * BB * HH;
    float* orow = out + (size_t)tt2 * BB * 2 * HH + (size_t)dir * HH + j0 + l15;
#pragma unroll
    for (int r = 0; r < 4; ++r) {
      float gi = acc[0][r] + bs[0];
      float gf = acc[1][r] + bs[1];
      float gg = acc[2][r] + bs[2];
      float go = acc[3][r] + bs[3];
      float si = 1.f / (1.f + __expf(-gi));
      float sf = 1.f / (1.f + __expf(-gf));
      float tg = 2.f / (1.f + __expf(-2.f * gg)) - 1.f;
      float so = 1.f / (1.f + __expf(-go));
      float c  = sf * cst[r] + si * tg;
      cst[r] = c;
      float th = 2.f / (1.f + __expf(-2.f * c)) - 1.f;
      float h  = so * th;
      int row = m0 + quad * 4 + r;
      hout[(size_t)row * HH + j0 + l15] = f2bf(h);
      orow[(size_t)row * 2 * HH] = h;
    }

    // ---- publish h_t ----
    __threadfence();      // drain + make h stores agent-visible
    __syncthreads();
    if (tid == 0)
      __hip_atomic_fetch_add(&cn[t], 1, __ATOMIC_RELEASE, __HIP_MEMORY_SCOPE_AGENT);
  }
}

extern "C" void kernel_launch(void* const* d_in, const int* in_sizes, int n_in,
                              void* d_out, int out_size, void* d_ws, size_t ws_size,
                              hipStream_t stream)
{
  (void)in_sizes; (void)n_in; (void)out_size;
  const float* x     = (const float*)d_in[0];
  const float* h0    = (const float*)d_in[1];
  const float* c0    = (const float*)d_in[2];
  const float* Wih_f = (const float*)d_in[3];
  const float* Whh_f = (const float*)d_in[4];
  const float* b_f   = (const float*)d_in[5];
  const float* Wih_b = (const float*)d_in[6];
  const float* Whh_b = (const float*)d_in[7];
  const float* b_b   = (const float*)d_in[8];
  float* out = (float*)d_out;
  char* ws = (char*)d_ws;

  const bool xbf = ws_size >= (WCAT_BYTES + XB_BYTES + HBUF_BYTES + CNT_BYTES);

  unsigned short* wcat = (unsigned short*)ws;
  unsigned short* xb = nullptr;
  unsigned short* hbuf;
  int* cnt;
  if (xbf) {
    xb   = (unsigned short*)(ws + WCAT_BYTES);
    hbuf = (unsigned short*)(ws + WCAT_BYTES + XB_BYTES);
    cnt  = (int*)(ws + WCAT_BYTES + XB_BYTES + HBUF_BYTES);
  } else {
    hbuf = (unsigned short*)(ws + WCAT_BYTES);
    cnt  = (int*)(ws + WCAT_BYTES + HBUF_BYTES);
  }

  prep_kernel<<<512, 256, 0, stream>>>(Wih_f, Whh_f, Wih_b, Whh_b, h0, wcat, hbuf, cnt);
  if (xbf) {
    xconv_kernel<<<2048, 256, 0, stream>>>(x, xb);
    lstm_kernel<true><<<64, 256, 0, stream>>>(x, xb, wcat, hbuf, cnt, c0, b_f, b_b, out);
  } else {
    lstm_kernel<false><<<64, 256, 0, stream>>>(x, xb, wcat, hbuf, cnt, c0, b_f, b_b, out);
  }
}

// Round 3
// 10573.927 us; speedup vs baseline: 1.1028x; 1.1028x over previous
//
#include <hip/hip_runtime.h>
#include <stdint.h>

#define TT 512
#define BB 64
#define II 512
#define HH 512
#define GG 2048   // 4H
#define KK 1024   // I + H

typedef short short8 __attribute__((ext_vector_type(8)));
typedef float floatx4 __attribute__((ext_vector_type(4)));

static constexpr size_t WCAT_BYTES = (size_t)2 * GG * KK * 2;       // 8 MB  bf16 [2][2048][1024]
static constexpr size_t XB_BYTES   = (size_t)TT * BB * II * 2;      // 32 MB bf16 [T][B][I]
// one flag per (dir,t,blk), padded to a 128B line each: [2][512][32] * 32 ints
static constexpr size_t FLAG_INTS  = (size_t)2 * TT * 32 * 32;      // 2^20 ints = 4 MB
static constexpr size_t FLAG_BYTES = FLAG_INTS * 4;

__device__ __forceinline__ unsigned short f2bf(float f) {
  unsigned int u = __float_as_uint(f);
  unsigned int r = (u + 0x7fffu + ((u >> 16) & 1u)) >> 16;   // round-to-nearest-even
  return (unsigned short)r;
}

// ---- prep: weights -> bf16 concat [dir][n][k] (k = [W_ih | W_hh]); zero flags
__global__ void prep_kernel(const float* __restrict__ Wih_f, const float* __restrict__ Whh_f,
                            const float* __restrict__ Wih_b, const float* __restrict__ Whh_b,
                            unsigned short* __restrict__ wcat,
                            int* __restrict__ flags)
{
  size_t tid0 = (size_t)blockIdx.x * blockDim.x + threadIdx.x;
  size_t stride = (size_t)gridDim.x * blockDim.x;

  const size_t WC = (size_t)2 * GG * KK;   // 2^22
  for (size_t idx = tid0; idx < WC; idx += stride) {
    int dir = (int)(idx >> 21);
    int rem = (int)(idx & ((1u << 21) - 1));
    int n = rem >> 10;
    int k = rem & 1023;
    const float* Wih = dir ? Wih_b : Wih_f;
    const float* Whh = dir ? Whh_b : Whh_f;
    float v = (k < II) ? Wih[(size_t)n * II + k] : Whh[(size_t)n * HH + (k - II)];
    wcat[idx] = f2bf(v);
  }

  for (size_t idx = tid0; idx < FLAG_INTS; idx += stride) flags[idx] = 0;
}

// ---- x -> bf16
__global__ void xconv_kernel(const float* __restrict__ x, unsigned short* __restrict__ xb) {
  size_t i = (size_t)blockIdx.x * blockDim.x + threadIdx.x;
  size_t stride = (size_t)gridDim.x * blockDim.x;
  const size_t n4 = (size_t)TT * BB * II / 4;
  const float4* xp = (const float4*)x;
  ushort4* op = (ushort4*)xb;
  for (; i < n4; i += stride) {
    float4 v = xp[i];
    ushort4 o;
    o.x = f2bf(v.x); o.y = f2bf(v.y); o.z = f2bf(v.z); o.w = f2bf(v.w);
    op[i] = o;
  }
}

// ---- persistent bidirectional LSTM
// grid = 64 blocks: dir = bid>>5, j-slice = (bid&31)*16. 4 waves/block: wave w owns
// m rows [16w,16w+16). c kept in registers for the whole sequence.
//
// Sync design (round 3):
//  * h state is exchanged through `out` itself (fp32, write-once per (t,b,j)):
//    per-t addresses => reader caches can never hold a stale copy => PLAIN loads
//    are coherent and co-XCD blocks share the L2 fill. No hbuf, no 16-bit atomics.
//  * writer: plain out stores -> __syncthreads (vmcnt drain) -> ONE release
//    fetch_add per block (buffer_wbl2 flushes dirty lines to L3, keeps clean
//    lines => weights stay L2-resident).
//  * reader: polls 32 per-block flags with relaxed atomic fetch_add(0) — RMWs
//    execute at the coherence point, guaranteeing progress WITHOUT buffer_inv.
//    Flags padded to one per 128B line to avoid L3 bank serialization.
template<bool XBF16>
__global__ __launch_bounds__(256, 1) void lstm_kernel(
    const float* __restrict__ x_f32,
    const unsigned short* __restrict__ xb,
    const unsigned short* __restrict__ wcat,
    int* __restrict__ flags,
    const float* __restrict__ h0,
    const float* __restrict__ c0,
    const float* __restrict__ b_f,
    const float* __restrict__ b_b,
    float* __restrict__ out)
{
  const int bid  = blockIdx.x;
  const int dir  = bid >> 5;
  const int blk  = bid & 31;
  const int j0   = blk << 4;
  const int tid  = threadIdx.x;
  const int lane = tid & 63;
  const int l15  = lane & 15;
  const int quad = lane >> 4;
  const int m0   = (tid >> 6) << 4;

  const unsigned short* Wd = wcat + (size_t)dir * GG * KK;
  const float* bias = dir ? b_b : b_f;

  float bs[4];
#pragma unroll
  for (int g = 0; g < 4; ++g) bs[g] = bias[g * HH + j0 + l15];

  // c state in registers: C/D layout -> row = m0 + quad*4 + r, col = j0 + l15
  float cst[4];
#pragma unroll
  for (int r = 0; r < 4; ++r)
    cst[r] = c0[(size_t)dir * BB * HH + (size_t)(m0 + quad * 4 + r) * HH + j0 + l15];

  const unsigned short* wrow[4];
#pragma unroll
  for (int g = 0; g < 4; ++g)
    wrow[g] = Wd + (size_t)(g * HH + j0 + l15) * KK + quad * 8;

  int* fl_dir = flags + ((size_t)dir * TT << 5) * 32;   // (dir,t,blk) at ((t<<5)+blk)*32

  for (int t = 0; t < TT; ++t) {
    const int tt2 = dir ? (TT - 1 - t) : t;

    floatx4 acc[4];
#pragma unroll
    for (int g = 0; g < 4; ++g) acc[g] = (floatx4){0.f, 0.f, 0.f, 0.f};

    // ---- x contribution (k = 0..511): independent of h, runs before the wait ----
    if (XBF16) {
      const unsigned short* arow = xb + (size_t)tt2 * BB * II + (size_t)(m0 + l15) * II + quad * 8;
#pragma unroll
      for (int kc = 0; kc < 16; ++kc) {
        short8 a = *(const short8*)(arow + kc * 32);
#pragma unroll
        for (int g = 0; g < 4; ++g) {
          short8 b = *(const short8*)(wrow[g] + kc * 32);
          acc[g] = __builtin_amdgcn_mfma_f32_16x16x32_bf16(a, b, acc[g], 0, 0, 0);
        }
      }
    } else {
      const float* arow = x_f32 + (size_t)tt2 * BB * II + (size_t)(m0 + l15) * II + quad * 8;
#pragma unroll
      for (int kc = 0; kc < 16; ++kc) {
        float4 v0 = *(const float4*)(arow + kc * 32);
        float4 v1 = *(const float4*)(arow + kc * 32 + 4);
        short8 a;
        a[0] = (short)f2bf(v0.x); a[1] = (short)f2bf(v0.y);
        a[2] = (short)f2bf(v0.z); a[3] = (short)f2bf(v0.w);
        a[4] = (short)f2bf(v1.x); a[5] = (short)f2bf(v1.y);
        a[6] = (short)f2bf(v1.z); a[7] = (short)f2bf(v1.w);
#pragma unroll
        for (int g = 0; g < 4; ++g) {
          short8 b = *(const short8*)(wrow[g] + kc * 32);
          acc[g] = __builtin_amdgcn_mfma_f32_16x16x32_bf16(a, b, acc[g], 0, 0, 0);
        }
      }
    }

    // ---- wait for h_{t-1}: every wave polls the 32 flags of step t-1 ----
    if (t > 0) {
      int* fl = fl_dir + ((((size_t)(t - 1)) << 5) + (lane & 31)) * 32;
      while (true) {
        int v = __hip_atomic_fetch_add(fl, 0, __ATOMIC_RELAXED, __HIP_MEMORY_SCOPE_AGENT);
        if (__ballot(v > 0) == ~0ull) break;
        __builtin_amdgcn_s_sleep(1);
      }
      asm volatile("" ::: "memory");   // compiler fence: keep h loads below the poll
    }

    // ---- h_{t-1} prefetch (fp32): from h0 at t=0, else from out[t_prev] ----
    const float* hrow;
    size_t rstride;
    if (t == 0) {
      hrow = h0 + (size_t)dir * BB * HH + (size_t)(m0 + l15) * HH + quad * 8;
      rstride = 0;  // already applied
    } else {
      const int tp = dir ? (TT - t) : (t - 1);  // previous step's output time index
      hrow = out + (size_t)tp * BB * 2 * HH + (size_t)(m0 + l15) * 2 * HH + (size_t)dir * HH + quad * 8;
      rstride = 0;
    }
    (void)rstride;
    float4 hv[32];
#pragma unroll
    for (int kc = 0; kc < 16; ++kc) {
      hv[2 * kc]     = *(const float4*)(hrow + (size_t)kc * 32);
      hv[2 * kc + 1] = *(const float4*)(hrow + (size_t)kc * 32 + 4);
    }

    // ---- h contribution (k = 512..1023) ----
#pragma unroll
    for (int kc = 0; kc < 16; ++kc) {
      float4 v0 = hv[2 * kc], v1 = hv[2 * kc + 1];
      short8 a;
      a[0] = (short)f2bf(v0.x); a[1] = (short)f2bf(v0.y);
      a[2] = (short)f2bf(v0.z); a[3] = (short)f2bf(v0.w);
      a[4] = (short)f2bf(v1.x); a[5] = (short)f2bf(v1.y);
      a[6] = (short)f2bf(v1.z); a[7] = (short)f2bf(v1.w);
#pragma unroll
      for (int g = 0; g < 4; ++g) {
        short8 b = *(const short8*)(wrow[g] + II + kc * 32);
        acc[g] = __builtin_amdgcn_mfma_f32_16x16x32_bf16(a, b, acc[g], 0, 0, 0);
      }
    }

    // ---- gates + state update + output (output IS the h exchange buffer) ----
    float* orow = out + (size_t)tt2 * BB * 2 * HH + (size_t)dir * HH + j0 + l15;
#pragma unroll
    for (int r = 0; r < 4; ++r) {
      float gi = acc[0][r] + bs[0];
      float gf = acc[1][r] + bs[1];
      float gg = acc[2][r] + bs[2];
      float go = acc[3][r] + bs[3];
      float si = 1.f / (1.f + __expf(-gi));
      float sf = 1.f / (1.f + __expf(-gf));
      float tg = 2.f / (1.f + __expf(-2.f * gg)) - 1.f;
      float so = 1.f / (1.f + __expf(-go));
      float c  = sf * cst[r] + si * tg;
      cst[r] = c;
      float th = 2.f / (1.f + __expf(-2.f * c)) - 1.f;
      float h  = so * th;
      int row = m0 + quad * 4 + r;
      orow[(size_t)row * 2 * HH] = h;
    }

    // ---- publish: barrier drains all waves' stores to L2, release RMW flushes
    //      this XCD's dirty lines to L3 (wbl2, no invalidate) and sets the flag ----
    __syncthreads();
    if (tid == 0)
      __hip_atomic_fetch_add(fl_dir + (((size_t)t << 5) + blk) * 32, 1,
                             __ATOMIC_RELEASE, __HIP_MEMORY_SCOPE_AGENT);
  }
}

extern "C" void kernel_launch(void* const* d_in, const int* in_sizes, int n_in,
                              void* d_out, int out_size, void* d_ws, size_t ws_size,
                              hipStream_t stream)
{
  (void)in_sizes; (void)n_in; (void)out_size;
  const float* x     = (const float*)d_in[0];
  const float* h0    = (const float*)d_in[1];
  const float* c0    = (const float*)d_in[2];
  const float* Wih_f = (const float*)d_in[3];
  const float* Whh_f = (const float*)d_in[4];
  const float* b_f   = (const float*)d_in[5];
  const float* Wih_b = (const float*)d_in[6];
  const float* Whh_b = (const float*)d_in[7];
  const float* b_b   = (const float*)d_in[8];
  float* out = (float*)d_out;
  char* ws = (char*)d_ws;

  const bool xbf = ws_size >= (WCAT_BYTES + XB_BYTES + FLAG_BYTES);

  unsigned short* wcat = (unsigned short*)ws;
  unsigned short* xb = nullptr;
  int* flags;
  if (xbf) {
    xb    = (unsigned short*)(ws + WCAT_BYTES);
    flags = (int*)(ws + WCAT_BYTES + XB_BYTES);
  } else {
    flags = (int*)(ws + WCAT_BYTES);
  }

  prep_kernel<<<512, 256, 0, stream>>>(Wih_f, Whh_f, Wih_b, Whh_b, wcat, flags);
  if (xbf) {
    xconv_kernel<<<2048, 256, 0, stream>>>(x, xb);
    lstm_kernel<true><<<64, 256, 0, stream>>>(x, xb, wcat, flags, h0, c0, b_f, b_b, out);
  } else {
    lstm_kernel<false><<<64, 256, 0, stream>>>(x, xb, wcat, flags, h0, c0, b_f, b_b, out);
  }
}

// Round 4
// 7033.207 us; speedup vs baseline: 1.6579x; 1.5034x over previous
//
#include <hip/hip_runtime.h>
#include <stdint.h>

#define TT 512
#define BB 64
#define II 512
#define HH 512
#define GG 2048   // 4H
#define KK 1024   // I + H

typedef short short8 __attribute__((ext_vector_type(8)));
typedef float floatx4 __attribute__((ext_vector_type(4)));

// workspace layout
static constexpr size_t WX_BYTES   = (size_t)2 * GG * II * 2;       // 4 MB bf16 [dir][2048][512]  x-part, row-major K
static constexpr size_t WH_BYTES   = (size_t)2 * 32 * 32768 * 2;    // 4 MB bf16 [dir][blk][32768] h-part LDS images
static constexpr size_t XB_BYTES   = (size_t)TT * BB * II * 2;      // 32 MB bf16 [T][B][I]
static constexpr size_t FLAG_INTS  = (size_t)2 * TT * 32 * 32;      // 4 MB: one flag per (dir,t,blk), 128B padded
static constexpr size_t FLAG_BYTES = FLAG_INTS * 4;

__device__ __forceinline__ unsigned short f2bf(float f) {
  unsigned int u = __float_as_uint(f);
  unsigned int r = (u + 0x7fffu + ((u >> 16) & 1u)) >> 16;   // round-to-nearest-even
  return (unsigned short)r;
}

// ---- prep: weights -> wx (x-part, [dir][n][k<512]) + wh (h-part, per-block LDS frag image
//      [g][kc][quad][j][8]); zero flags
__global__ void prep_kernel(const float* __restrict__ Wih_f, const float* __restrict__ Whh_f,
                            const float* __restrict__ Wih_b, const float* __restrict__ Whh_b,
                            unsigned short* __restrict__ wx,
                            unsigned short* __restrict__ wh,
                            int* __restrict__ flags)
{
  size_t tid0 = (size_t)blockIdx.x * blockDim.x + threadIdx.x;
  size_t stride = (size_t)gridDim.x * blockDim.x;

  const size_t WC = (size_t)2 * GG * KK;   // 2^22
  for (size_t idx = tid0; idx < WC; idx += stride) {
    int dir = (int)(idx >> 21);
    int rem = (int)(idx & ((1u << 21) - 1));
    int n = rem >> 10;        // 0..2047
    int k = rem & 1023;       // 0..1023
    if (k < II) {
      const float* Wih = dir ? Wih_b : Wih_f;
      wx[(size_t)dir * GG * II + (size_t)n * II + k] = f2bf(Wih[(size_t)n * II + k]);
    } else {
      const float* Whh = dir ? Whh_b : Whh_f;
      int kk = k - II;            // 0..511
      int kc = kk >> 5;           // 0..15
      int r  = kk & 31;
      int quad = r >> 3;          // 0..3
      int e  = r & 7;             // 0..7
      int g   = n >> 9;           // 0..3
      int blk = (n >> 4) & 31;    // 0..31
      int j   = n & 15;           // 0..15
      size_t lidx = ((size_t)((g * 16 + kc) * 4 + quad) * 16 + j) * 8 + e;
      wh[((size_t)dir * 32 + blk) * 32768 + lidx] = f2bf(Whh[(size_t)n * HH + kk]);
    }
  }

  for (size_t idx = tid0; idx < FLAG_INTS; idx += stride) flags[idx] = 0;
}

// ---- x -> bf16
__global__ void xconv_kernel(const float* __restrict__ x, unsigned short* __restrict__ xb) {
  size_t i = (size_t)blockIdx.x * blockDim.x + threadIdx.x;
  size_t stride = (size_t)gridDim.x * blockDim.x;
  const size_t n4 = (size_t)TT * BB * II / 4;
  const float4* xp = (const float4*)x;
  ushort4* op = (ushort4*)xb;
  for (; i < n4; i += stride) {
    float4 v = xp[i];
    ushort4 o;
    o.x = f2bf(v.x); o.y = f2bf(v.y); o.z = f2bf(v.z); o.w = f2bf(v.w);
    op[i] = o;
  }
}

// ---- persistent bidirectional LSTM
// grid = 64 blocks: dir = bid>>5, j-slice = (bid&31)*16. 4 waves/block (wave = m-tile).
// Round-4 changes vs round 3 (which sat at 20.6 us/step, FETCH showed ~1 MB/step
// of HBM weight refetch on the critical path):
//  * h-part weights (64 KB/block) live in LDS, staged once — the post-wait GEMM's
//    B-operand is immune to L2/MALL eviction. Pre-permuted frag image, ds_read_b128.
//  * x-part weights stream from a compact global wx; that half runs BEFORE the
//    inter-block wait, so its misses overlap waiting.
//  * poll RMW storm cut 8x: wave 0 lanes<32 poll with s_sleep backoff, then
//    __syncthreads releases the block.
template<bool XBF16>
__global__ __launch_bounds__(256, 1) void lstm_kernel(
    const float* __restrict__ x_f32,
    const unsigned short* __restrict__ xb,
    const unsigned short* __restrict__ wx,
    const unsigned short* __restrict__ wh,
    int* __restrict__ flags,
    const float* __restrict__ h0,
    const float* __restrict__ c0,
    const float* __restrict__ b_f,
    const float* __restrict__ b_b,
    float* __restrict__ out)
{
  __shared__ unsigned short w_lds[32768];   // 64 KB: [g][kc][quad][j][8]

  const int bid  = blockIdx.x;
  const int dir  = bid >> 5;
  const int blk  = bid & 31;
  const int j0   = blk << 4;
  const int tid  = threadIdx.x;
  const int lane = tid & 63;
  const int l15  = lane & 15;
  const int quad = lane >> 4;
  const int m0   = (tid >> 6) << 4;

  // stage h-part weights into LDS (once)
  {
    const uint4* src = (const uint4*)(wh + ((size_t)dir * 32 + blk) * 32768);
    uint4* dst = (uint4*)w_lds;
#pragma unroll
    for (int i = 0; i < 16; ++i) dst[tid + 256 * i] = src[tid + 256 * i];
  }

  const float* bias = dir ? b_b : b_f;
  float bs[4];
#pragma unroll
  for (int g = 0; g < 4; ++g) bs[g] = bias[g * HH + j0 + l15];

  // c state in registers: C/D layout -> row = m0 + quad*4 + r, col = j0 + l15
  float cst[4];
#pragma unroll
  for (int r = 0; r < 4; ++r)
    cst[r] = c0[(size_t)dir * BB * HH + (size_t)(m0 + quad * 4 + r) * HH + j0 + l15];

  // x-part B row pointers (global, [n][k<512])
  const unsigned short* wxrow[4];
#pragma unroll
  for (int g = 0; g < 4; ++g)
    wxrow[g] = wx + (size_t)dir * GG * II + (size_t)(g * HH + j0 + l15) * II + quad * 8;

  // LDS per-lane base (shorts): quad*128 + l15*8; gate/kc step = 512 shorts
  const int wl_base = quad * 128 + l15 * 8;

  int* fl_dir = flags + ((size_t)dir * TT) * 32 * 32;

  __syncthreads();   // LDS weights ready

  for (int t = 0; t < TT; ++t) {
    const int tt2 = dir ? (TT - 1 - t) : t;

    floatx4 acc[4];
#pragma unroll
    for (int g = 0; g < 4; ++g) acc[g] = (floatx4){0.f, 0.f, 0.f, 0.f};

    // ---- x contribution (k = 0..511): independent of h, overlaps the wait ----
    if (XBF16) {
      const unsigned short* arow = xb + (size_t)tt2 * BB * II + (size_t)(m0 + l15) * II + quad * 8;
#pragma unroll
      for (int kc = 0; kc < 16; ++kc) {
        short8 a = *(const short8*)(arow + kc * 32);
#pragma unroll
        for (int g = 0; g < 4; ++g) {
          short8 b = *(const short8*)(wxrow[g] + kc * 32);
          acc[g] = __builtin_amdgcn_mfma_f32_16x16x32_bf16(a, b, acc[g], 0, 0, 0);
        }
      }
    } else {
      const float* arow = x_f32 + (size_t)tt2 * BB * II + (size_t)(m0 + l15) * II + quad * 8;
#pragma unroll
      for (int kc = 0; kc < 16; ++kc) {
        float4 v0 = *(const float4*)(arow + kc * 32);
        float4 v1 = *(const float4*)(arow + kc * 32 + 4);
        short8 a;
        a[0] = (short)f2bf(v0.x); a[1] = (short)f2bf(v0.y);
        a[2] = (short)f2bf(v0.z); a[3] = (short)f2bf(v0.w);
        a[4] = (short)f2bf(v1.x); a[5] = (short)f2bf(v1.y);
        a[6] = (short)f2bf(v1.z); a[7] = (short)f2bf(v1.w);
#pragma unroll
        for (int g = 0; g < 4; ++g) {
          short8 b = *(const short8*)(wxrow[g] + kc * 32);
          acc[g] = __builtin_amdgcn_mfma_f32_16x16x32_bf16(a, b, acc[g], 0, 0, 0);
        }
      }
    }

    // ---- wait for h_{t-1}: wave 0 lanes<32 poll, barrier releases the block ----
    if (t > 0) {
      if (tid < 64) {
        int v = 1;
        int* fl = fl_dir + (((size_t)(t - 1) << 5) + (lane & 31)) * 32;
        while (true) {
          if (lane < 32)
            v = __hip_atomic_fetch_add(fl, 0, __ATOMIC_RELAXED, __HIP_MEMORY_SCOPE_AGENT);
          if (__ballot(v > 0) == ~0ull) break;
          __builtin_amdgcn_s_sleep(2);
        }
      }
      __syncthreads();
      asm volatile("" ::: "memory");   // keep h loads below the wait
    }

    // ---- h_{t-1} loads (fp32): from h0 at t=0, else from out[t_prev] ----
    const float* hrow;
    if (t == 0) {
      hrow = h0 + (size_t)dir * BB * HH + (size_t)(m0 + l15) * HH + quad * 8;
    } else {
      const int tp = dir ? (TT - t) : (t - 1);
      hrow = out + (size_t)tp * BB * 2 * HH + (size_t)(m0 + l15) * 2 * HH + (size_t)dir * HH + quad * 8;
    }
    float4 hv[32];
#pragma unroll
    for (int kc = 0; kc < 16; ++kc) {
      hv[2 * kc]     = *(const float4*)(hrow + (size_t)kc * 32);
      hv[2 * kc + 1] = *(const float4*)(hrow + (size_t)kc * 32 + 4);
    }

    // ---- h contribution (k = 512..1023), B from LDS ----
#pragma unroll
    for (int kc = 0; kc < 16; ++kc) {
      float4 v0 = hv[2 * kc], v1 = hv[2 * kc + 1];
      short8 a;
      a[0] = (short)f2bf(v0.x); a[1] = (short)f2bf(v0.y);
      a[2] = (short)f2bf(v0.z); a[3] = (short)f2bf(v0.w);
      a[4] = (short)f2bf(v1.x); a[5] = (short)f2bf(v1.y);
      a[6] = (short)f2bf(v1.z); a[7] = (short)f2bf(v1.w);
#pragma unroll
      for (int g = 0; g < 4; ++g) {
        short8 b = *(const short8*)(&w_lds[(g * 16 + kc) * 512 + wl_base]);
        acc[g] = __builtin_amdgcn_mfma_f32_16x16x32_bf16(a, b, acc[g], 0, 0, 0);
      }
    }

    // ---- gates + state update + output (output IS the h exchange buffer) ----
    float* orow = out + (size_t)tt2 * BB * 2 * HH + (size_t)dir * HH + j0 + l15;
#pragma unroll
    for (int r = 0; r < 4; ++r) {
      float gi = acc[0][r] + bs[0];
      float gf = acc[1][r] + bs[1];
      float gg = acc[2][r] + bs[2];
      float go = acc[3][r] + bs[3];
      float si = 1.f / (1.f + __expf(-gi));
      float sf = 1.f / (1.f + __expf(-gf));
      float tg = 2.f / (1.f + __expf(-2.f * gg)) - 1.f;
      float so = 1.f / (1.f + __expf(-go));
      float c  = sf * cst[r] + si * tg;
      cst[r] = c;
      float th = 2.f / (1.f + __expf(-2.f * c)) - 1.f;
      float h  = so * th;
      int row = m0 + quad * 4 + r;
      orow[(size_t)row * 2 * HH] = h;
    }

    // ---- publish: barrier drains stores, release RMW flushes dirty lines + sets flag ----
    __syncthreads();
    if (tid == 0)
      __hip_atomic_fetch_add(fl_dir + (((size_t)t << 5) + blk) * 32, 1,
                             __ATOMIC_RELEASE, __HIP_MEMORY_SCOPE_AGENT);
  }
}

extern "C" void kernel_launch(void* const* d_in, const int* in_sizes, int n_in,
                              void* d_out, int out_size, void* d_ws, size_t ws_size,
                              hipStream_t stream)
{
  (void)in_sizes; (void)n_in; (void)out_size;
  const float* x     = (const float*)d_in[0];
  const float* h0    = (const float*)d_in[1];
  const float* c0    = (const float*)d_in[2];
  const float* Wih_f = (const float*)d_in[3];
  const float* Whh_f = (const float*)d_in[4];
  const float* b_f   = (const float*)d_in[5];
  const float* Wih_b = (const float*)d_in[6];
  const float* Whh_b = (const float*)d_in[7];
  const float* b_b   = (const float*)d_in[8];
  float* out = (float*)d_out;
  char* ws = (char*)d_ws;

  const bool xbf = ws_size >= (WX_BYTES + WH_BYTES + XB_BYTES + FLAG_BYTES);

  unsigned short* wx = (unsigned short*)ws;
  unsigned short* wh = (unsigned short*)(ws + WX_BYTES);
  unsigned short* xb = nullptr;
  int* flags;
  if (xbf) {
    xb    = (unsigned short*)(ws + WX_BYTES + WH_BYTES);
    flags = (int*)(ws + WX_BYTES + WH_BYTES + XB_BYTES);
  } else {
    flags = (int*)(ws + WX_BYTES + WH_BYTES);
  }

  prep_kernel<<<512, 256, 0, stream>>>(Wih_f, Whh_f, Wih_b, Whh_b, wx, wh, flags);
  if (xbf) {
    xconv_kernel<<<2048, 256, 0, stream>>>(x, xb);
    lstm_kernel<true><<<64, 256, 0, stream>>>(x, xb, wx, wh, flags, h0, c0, b_f, b_b, out);
  } else {
    lstm_kernel<false><<<64, 256, 0, stream>>>(x, xb, wx, wh, flags, h0, c0, b_f, b_b, out);
  }
}